// Round 1
// baseline (981.805 us; speedup 1.0000x reference)
//
#include <hip/hip_runtime.h>

// Problem constants (fixed by the reference's config)
#define HH 480
#define WW 640
#define NN (HH * WW)
#define BB 8
#define PP 4
#define EPS 1e-9f

// Scatter: one thread per (batch, pixel). Reads flow plane i, warps the grid
// point, and atomically splats bilinear weights + weighted flow into the
// three accumulators in workspace.
__global__ void splat_kernel(const float* __restrict__ fx_all,
                             const float* __restrict__ fy_all,
                             const int* __restrict__ i_ptr,
                             const int* __restrict__ tref_ptr,
                             float* __restrict__ sum_w,
                             float* __restrict__ sum_wy,
                             float* __restrict__ sum_wx) {
    int t = blockIdx.x * blockDim.x + threadIdx.x;
    if (t >= BB * NN) return;
    int b = t / NN;
    int p = t - b * NN;

    int i = *i_ptr;
    float dt = (float)(*tref_ptr - i);

    const float fx = fx_all[(b * PP + i) * NN + p];
    const float fy = fy_all[(b * PP + i) * NN + p];

    float gy = (float)(p / WW);
    float gx = (float)(p - (p / WW) * WW);

    float wy = gy + dt * fy;   // warped y
    float wx = gx + dt * fx;   // warped x

    // purge_unfeasible: points leaving the image contribute v = 0 everywhere.
    bool inside = (wy >= 0.0f) && (wy <= (float)(HH - 1)) &&
                  (wx >= 0.0f) && (wx <= (float)(WW - 1));
    if (!inside) return;

    float ty = floorf(wy);
    float lx = floorf(wx);

    int base = b * NN;

#pragma unroll
    for (int k = 0; k < 4; ++k) {
        float ny = ty + (float)(k >> 1);
        float nx = lx + (float)(k & 1);
        // Neighbors outside [0,H)x[0,W) carry exactly-zero weight (or are
        // dropped by the reference's mode='drop') -> skip.
        int iy = (int)ny;
        int ix = (int)nx;
        if (iy < 0 || iy >= HH || ix < 0 || ix >= WW) continue;
        // weights = clip(1-|dy|,0,1) * clip(1-|dx|,0,1), same as reference
        float wgt_y = fminf(fmaxf(1.0f - fabsf(wy - ny), 0.0f), 1.0f);
        float wgt_x = fminf(fmaxf(1.0f - fabsf(wx - nx), 0.0f), 1.0f);
        float w = wgt_y * wgt_x;
        int fi = base + iy * WW + ix;
        atomicAdd(&sum_w[fi],  w);
        atomicAdd(&sum_wy[fi], w * fy);
        atomicAdd(&sum_wx[fi], w * fx);
    }
}

// Finalize: out[0 .. B*N) = flow_x, out[B*N .. 2*B*N) = flow_y
__global__ void finalize_kernel(const float* __restrict__ sum_w,
                                const float* __restrict__ sum_wy,
                                const float* __restrict__ sum_wx,
                                float* __restrict__ out) {
    int t = blockIdx.x * blockDim.x + threadIdx.x;
    if (t >= BB * NN) return;
    float denom = sum_w[t] + EPS;
    out[t]           = sum_wx[t] / denom;
    out[BB * NN + t] = sum_wy[t] / denom;
}

extern "C" void kernel_launch(void* const* d_in, const int* in_sizes, int n_in,
                              void* d_out, int out_size, void* d_ws, size_t ws_size,
                              hipStream_t stream) {
    const float* fx_all = (const float*)d_in[0];
    const float* fy_all = (const float*)d_in[1];
    const int* i_ptr    = (const int*)d_in[2];
    const int* tref_ptr = (const int*)d_in[3];
    float* out = (float*)d_out;

    float* sum_w  = (float*)d_ws;
    float* sum_wy = sum_w  + BB * NN;
    float* sum_wx = sum_wy + BB * NN;

    // Zero the accumulators every call (harness does not re-poison between
    // replays; we must not rely on prior state).
    hipMemsetAsync(d_ws, 0, (size_t)3 * BB * NN * sizeof(float), stream);

    int total = BB * NN;
    int block = 256;
    int grid = (total + block - 1) / block;
    splat_kernel<<<grid, block, 0, stream>>>(fx_all, fy_all, i_ptr, tref_ptr,
                                             sum_w, sum_wy, sum_wx);
    finalize_kernel<<<grid, block, 0, stream>>>(sum_w, sum_wy, sum_wx, out);
}

// Round 2
// 214.779 us; speedup vs baseline: 4.5712x; 4.5712x over previous
//
#include <hip/hip_runtime.h>

// Problem constants (fixed by the reference's config)
#define HH 480
#define WW 640
#define NN (HH * WW)
#define BB 8
#define PP 4
#define EPS 1e-9f

// Tiled-staging geometry
#define TS 48                    // source tile edge
#define RR 12                    // halo (covers |disp| <= 12; dt*N(0,1), dt=4 -> 3 sigma)
#define EXT (TS + 2 * RR)        // 72 staged edge
#define EXT2 (EXT * EXT)         // 5184 staged pixels
#define SFLOATS (EXT2 * 3)       // 15552 floats = 62208 B LDS
#define NTX ((WW + TS - 1) / TS) // 14
#define NTY ((HH + TS - 1) / TS) // 10
#define NTILES (NTX * NTY)       // 140

// ---------------- staged path ----------------

__global__ __launch_bounds__(256)
void splat_stage(const float* __restrict__ fx_all,
                 const float* __restrict__ fy_all,
                 const int* __restrict__ i_ptr,
                 const int* __restrict__ tref_ptr,
                 float* __restrict__ S,
                 float* __restrict__ Fw,
                 float* __restrict__ Fwy,
                 float* __restrict__ Fwx) {
    __shared__ float sacc[SFLOATS];
    const int tid = threadIdx.x;
    for (int e = tid; e < SFLOATS; e += 256) sacc[e] = 0.0f;
    __syncthreads();

    const int txi = blockIdx.x, tyi = blockIdx.y, b = blockIdx.z;
    const int tx0 = txi * TS, ty0 = tyi * TS;
    const int i = *i_ptr;
    const float dt = (float)(*tref_ptr - i);
    const float* __restrict__ fxp = fx_all + (size_t)(b * PP + i) * NN;
    const float* __restrict__ fyp = fy_all + (size_t)(b * PP + i) * NN;

    for (int sp = tid; sp < TS * TS; sp += 256) {
        int sy = sp / TS, sx = sp - sy * TS;
        int gy = ty0 + sy, gx = tx0 + sx;
        if (gy >= HH || gx >= WW) continue;
        int p = gy * WW + gx;
        float fx = fxp[p], fy = fyp[p];
        float wyf = (float)gy + dt * fy;
        float wxf = (float)gx + dt * fx;
        // purge_unfeasible
        if (!(wyf >= 0.0f && wyf <= (float)(HH - 1) &&
              wxf >= 0.0f && wxf <= (float)(WW - 1))) continue;
        float tyf = floorf(wyf), lxf = floorf(wxf);
        float fry = wyf - tyf, frx = wxf - lxf;
        int iy0 = (int)tyf, ix0 = (int)lxf;
        float wts[4] = {(1.0f - fry) * (1.0f - frx),
                        (1.0f - fry) * frx,
                        fry * (1.0f - frx),
                        fry * frx};
#pragma unroll
        for (int k = 0; k < 4; ++k) {
            int iy = iy0 + (k >> 1), ix = ix0 + (k & 1);
            if (iy >= HH || ix >= WW) continue;  // iy,ix >= 0 guaranteed (inside test)
            float w = wts[k];
            int ly = iy - (ty0 - RR), lx = ix - (tx0 - RR);
            if ((unsigned)ly < (unsigned)EXT && (unsigned)lx < (unsigned)EXT) {
                int e = (ly * EXT + lx) * 3;
                atomicAdd(&sacc[e + 0], w);
                atomicAdd(&sacc[e + 1], w * fy);
                atomicAdd(&sacc[e + 2], w * fx);
            } else {
                // rare (~2e-4): out-of-halo splat -> global fallback accumulator
                int fi = b * NN + iy * WW + ix;
                atomicAdd(&Fw[fi], w);
                atomicAdd(&Fwy[fi], w * fy);
                atomicAdd(&Fwx[fi], w * fx);
            }
        }
    }
    __syncthreads();

    // Flush LDS tile to per-tile staging with plain coalesced stores.
    float* __restrict__ St = S + (size_t)(b * NTILES + tyi * NTX + txi) * SFLOATS;
    for (int e = tid; e < SFLOATS; e += 256) St[e] = sacc[e];
}

__global__ __launch_bounds__(256)
void gather_finalize(const float* __restrict__ S,
                     const float* __restrict__ Fw,
                     const float* __restrict__ Fwy,
                     const float* __restrict__ Fwx,
                     float* __restrict__ out) {
    int t = blockIdx.x * blockDim.x + threadIdx.x;
    if (t >= BB * NN) return;
    int b = t / NN, p = t - b * NN;
    int y = p / WW, x = p - y * WW;

    float w = Fw[t], wy = Fwy[t], wx = Fwx[t];

    // tiles whose staged region [t0-RR, t0+TS-1+RR] covers (y,x)
    int ty_lo = y - (TS - 1 + RR);
    ty_lo = ty_lo > 0 ? (ty_lo + TS - 1) / TS : 0;
    int ty_hi = (y + RR) / TS; if (ty_hi > NTY - 1) ty_hi = NTY - 1;
    int tx_lo = x - (TS - 1 + RR);
    tx_lo = tx_lo > 0 ? (tx_lo + TS - 1) / TS : 0;
    int tx_hi = (x + RR) / TS; if (tx_hi > NTX - 1) tx_hi = NTX - 1;

    for (int tyi = ty_lo; tyi <= ty_hi; ++tyi) {
        int ly = y - (tyi * TS - RR);
        for (int txi = tx_lo; txi <= tx_hi; ++txi) {
            int lx = x - (txi * TS - RR);
            const float* __restrict__ St =
                S + (size_t)(b * NTILES + tyi * NTX + txi) * SFLOATS + (ly * EXT + lx) * 3;
            w  += St[0];
            wy += St[1];
            wx += St[2];
        }
    }
    float denom = w + EPS;
    out[t] = wx / denom;
    out[(size_t)BB * NN + t] = wy / denom;
}

// ---------------- fallback path (R1, needs only 29.5 MB ws) ----------------

__global__ void splat_kernel(const float* __restrict__ fx_all,
                             const float* __restrict__ fy_all,
                             const int* __restrict__ i_ptr,
                             const int* __restrict__ tref_ptr,
                             float* __restrict__ sum_w,
                             float* __restrict__ sum_wy,
                             float* __restrict__ sum_wx) {
    int t = blockIdx.x * blockDim.x + threadIdx.x;
    if (t >= BB * NN) return;
    int b = t / NN;
    int p = t - b * NN;
    int i = *i_ptr;
    float dt = (float)(*tref_ptr - i);
    const float fx = fx_all[(size_t)(b * PP + i) * NN + p];
    const float fy = fy_all[(size_t)(b * PP + i) * NN + p];
    float gy = (float)(p / WW);
    float gx = (float)(p - (p / WW) * WW);
    float wy = gy + dt * fy;
    float wx = gx + dt * fx;
    bool inside = (wy >= 0.0f) && (wy <= (float)(HH - 1)) &&
                  (wx >= 0.0f) && (wx <= (float)(WW - 1));
    if (!inside) return;
    float ty = floorf(wy);
    float lx = floorf(wx);
    int base = b * NN;
#pragma unroll
    for (int k = 0; k < 4; ++k) {
        float ny = ty + (float)(k >> 1);
        float nx = lx + (float)(k & 1);
        int iy = (int)ny;
        int ix = (int)nx;
        if (iy < 0 || iy >= HH || ix < 0 || ix >= WW) continue;
        float wgt_y = fminf(fmaxf(1.0f - fabsf(wy - ny), 0.0f), 1.0f);
        float wgt_x = fminf(fmaxf(1.0f - fabsf(wx - nx), 0.0f), 1.0f);
        float w = wgt_y * wgt_x;
        int fi = base + iy * WW + ix;
        atomicAdd(&sum_w[fi],  w);
        atomicAdd(&sum_wy[fi], w * fy);
        atomicAdd(&sum_wx[fi], w * fx);
    }
}

__global__ void finalize_kernel(const float* __restrict__ sum_w,
                                const float* __restrict__ sum_wy,
                                const float* __restrict__ sum_wx,
                                float* __restrict__ out) {
    int t = blockIdx.x * blockDim.x + threadIdx.x;
    if (t >= BB * NN) return;
    float denom = sum_w[t] + EPS;
    out[t]                   = sum_wx[t] / denom;
    out[(size_t)BB * NN + t] = sum_wy[t] / denom;
}

// ---------------- launch ----------------

extern "C" void kernel_launch(void* const* d_in, const int* in_sizes, int n_in,
                              void* d_out, int out_size, void* d_ws, size_t ws_size,
                              hipStream_t stream) {
    const float* fx_all = (const float*)d_in[0];
    const float* fy_all = (const float*)d_in[1];
    const int* i_ptr    = (const int*)d_in[2];
    const int* tref_ptr = (const int*)d_in[3];
    float* out = (float*)d_out;

    const size_t S_bytes = (size_t)BB * NTILES * SFLOATS * sizeof(float); // ~69.7 MB
    const size_t F_elems = (size_t)BB * NN;
    const size_t F_bytes = F_elems * 3 * sizeof(float);                   // ~29.5 MB

    if (ws_size >= S_bytes + F_bytes) {
        float* S   = (float*)d_ws;
        float* Fw  = (float*)((char*)d_ws + S_bytes);
        float* Fwy = Fw + F_elems;
        float* Fwx = Fwy + F_elems;
        // Zero only the fallback accumulator; S is fully overwritten by flush.
        hipMemsetAsync(Fw, 0, F_bytes, stream);
        splat_stage<<<dim3(NTX, NTY, BB), 256, 0, stream>>>(
            fx_all, fy_all, i_ptr, tref_ptr, S, Fw, Fwy, Fwx);
        int total = BB * NN;
        gather_finalize<<<(total + 255) / 256, 256, 0, stream>>>(S, Fw, Fwy, Fwx, out);
    } else {
        // R1 fallback: plain global-atomic splat
        float* sum_w  = (float*)d_ws;
        float* sum_wy = sum_w + (size_t)BB * NN;
        float* sum_wx = sum_wy + (size_t)BB * NN;
        hipMemsetAsync(d_ws, 0, (size_t)3 * BB * NN * sizeof(float), stream);
        int total = BB * NN;
        int block = 256;
        int grid = (total + block - 1) / block;
        splat_kernel<<<grid, block, 0, stream>>>(fx_all, fy_all, i_ptr, tref_ptr,
                                                 sum_w, sum_wy, sum_wx);
        finalize_kernel<<<grid, block, 0, stream>>>(sum_w, sum_wy, sum_wx, out);
    }
}

// Round 3
// 214.763 us; speedup vs baseline: 4.5716x; 1.0001x over previous
//
#include <hip/hip_runtime.h>

// Problem constants (fixed by the reference's config)
#define HH 480
#define WW 640
#define NN (HH * WW)
#define BB 8
#define PP 4
#define EPS 1e-9f

// Tiled-staging geometry
#define TS 48                    // source tile edge
#define RR 12                    // halo (covers |disp| <= 12; dt*N(0,1), dt=4 -> 3 sigma)
#define EXT (TS + 2 * RR)        // 72 staged edge
#define EXT2 (EXT * EXT)         // 5184 staged pixels
#define SFLOATS (EXT2 * 3)       // 15552 floats = 62208 B LDS
#define NTX ((WW + TS - 1) / TS) // 14
#define NTY ((HH + TS - 1) / TS) // 10
#define NTILES (NTX * NTY)       // 140

// Native f32 atomic add (ds_add_f32 / global_atomic_add_f32). Default
// atomicAdd(float*) compiles to a CAS retry loop on gfx9xx (denorm-safe),
// ~250 cy/wave-op measured in R2. Denorm flushing is irrelevant at our
// magnitudes (weights in [0,1], flow ~N(0,1), threshold 0.108).
__device__ __forceinline__ void atomic_add_f32(float* p, float v) {
    unsafeAtomicAdd(p, v);
}

// ---------------- staged path ----------------

__global__ __launch_bounds__(256)
void splat_stage(const float* __restrict__ fx_all,
                 const float* __restrict__ fy_all,
                 const int* __restrict__ i_ptr,
                 const int* __restrict__ tref_ptr,
                 float* __restrict__ S,
                 float* __restrict__ Fw,
                 float* __restrict__ Fwy,
                 float* __restrict__ Fwx) {
    __shared__ float sacc[SFLOATS];
    const int tid = threadIdx.x;
    for (int e = tid; e < SFLOATS; e += 256) sacc[e] = 0.0f;
    __syncthreads();

    const int txi = blockIdx.x, tyi = blockIdx.y, b = blockIdx.z;
    const int tx0 = txi * TS, ty0 = tyi * TS;
    const int i = *i_ptr;
    const float dt = (float)(*tref_ptr - i);
    const float* __restrict__ fxp = fx_all + (size_t)(b * PP + i) * NN;
    const float* __restrict__ fyp = fy_all + (size_t)(b * PP + i) * NN;

    for (int sp = tid; sp < TS * TS; sp += 256) {
        int sy = sp / TS, sx = sp - sy * TS;
        int gy = ty0 + sy, gx = tx0 + sx;
        if (gy >= HH || gx >= WW) continue;
        int p = gy * WW + gx;
        float fx = fxp[p], fy = fyp[p];
        float wyf = (float)gy + dt * fy;
        float wxf = (float)gx + dt * fx;
        // purge_unfeasible
        if (!(wyf >= 0.0f && wyf <= (float)(HH - 1) &&
              wxf >= 0.0f && wxf <= (float)(WW - 1))) continue;
        float tyf = floorf(wyf), lxf = floorf(wxf);
        float fry = wyf - tyf, frx = wxf - lxf;
        int iy0 = (int)tyf, ix0 = (int)lxf;
        float wts[4] = {(1.0f - fry) * (1.0f - frx),
                        (1.0f - fry) * frx,
                        fry * (1.0f - frx),
                        fry * frx};
#pragma unroll
        for (int k = 0; k < 4; ++k) {
            int iy = iy0 + (k >> 1), ix = ix0 + (k & 1);
            if (iy >= HH || ix >= WW) continue;  // iy,ix >= 0 guaranteed (inside test)
            float w = wts[k];
            int ly = iy - (ty0 - RR), lx = ix - (tx0 - RR);
            if ((unsigned)ly < (unsigned)EXT && (unsigned)lx < (unsigned)EXT) {
                int e = (ly * EXT + lx) * 3;
                atomic_add_f32(&sacc[e + 0], w);
                atomic_add_f32(&sacc[e + 1], w * fy);
                atomic_add_f32(&sacc[e + 2], w * fx);
            } else {
                // rare (~2e-4): out-of-halo splat -> global fallback accumulator
                int fi = b * NN + iy * WW + ix;
                atomic_add_f32(&Fw[fi], w);
                atomic_add_f32(&Fwy[fi], w * fy);
                atomic_add_f32(&Fwx[fi], w * fx);
            }
        }
    }
    __syncthreads();

    // Flush LDS tile to per-tile staging with plain coalesced stores.
    float* __restrict__ St = S + (size_t)(b * NTILES + tyi * NTX + txi) * SFLOATS;
    for (int e = tid; e < SFLOATS; e += 256) St[e] = sacc[e];
}

__global__ __launch_bounds__(256)
void gather_finalize(const float* __restrict__ S,
                     const float* __restrict__ Fw,
                     const float* __restrict__ Fwy,
                     const float* __restrict__ Fwx,
                     float* __restrict__ out) {
    int t = blockIdx.x * blockDim.x + threadIdx.x;
    if (t >= BB * NN) return;
    int b = t / NN, p = t - b * NN;
    int y = p / WW, x = p - y * WW;

    float w = Fw[t], wy = Fwy[t], wx = Fwx[t];

    // tiles whose staged region [t0-RR, t0+TS-1+RR] covers (y,x)
    int ty_lo = y - (TS - 1 + RR);
    ty_lo = ty_lo > 0 ? (ty_lo + TS - 1) / TS : 0;
    int ty_hi = (y + RR) / TS; if (ty_hi > NTY - 1) ty_hi = NTY - 1;
    int tx_lo = x - (TS - 1 + RR);
    tx_lo = tx_lo > 0 ? (tx_lo + TS - 1) / TS : 0;
    int tx_hi = (x + RR) / TS; if (tx_hi > NTX - 1) tx_hi = NTX - 1;

    for (int tyi = ty_lo; tyi <= ty_hi; ++tyi) {
        int ly = y - (tyi * TS - RR);
        for (int txi = tx_lo; txi <= tx_hi; ++txi) {
            int lx = x - (txi * TS - RR);
            const float* __restrict__ St =
                S + (size_t)(b * NTILES + tyi * NTX + txi) * SFLOATS + (ly * EXT + lx) * 3;
            w  += St[0];
            wy += St[1];
            wx += St[2];
        }
    }
    float denom = w + EPS;
    out[t] = wx / denom;
    out[(size_t)BB * NN + t] = wy / denom;
}

// ---------------- fallback path (R1, needs only 29.5 MB ws) ----------------

__global__ void splat_kernel(const float* __restrict__ fx_all,
                             const float* __restrict__ fy_all,
                             const int* __restrict__ i_ptr,
                             const int* __restrict__ tref_ptr,
                             float* __restrict__ sum_w,
                             float* __restrict__ sum_wy,
                             float* __restrict__ sum_wx) {
    int t = blockIdx.x * blockDim.x + threadIdx.x;
    if (t >= BB * NN) return;
    int b = t / NN;
    int p = t - b * NN;
    int i = *i_ptr;
    float dt = (float)(*tref_ptr - i);
    const float fx = fx_all[(size_t)(b * PP + i) * NN + p];
    const float fy = fy_all[(size_t)(b * PP + i) * NN + p];
    float gy = (float)(p / WW);
    float gx = (float)(p - (p / WW) * WW);
    float wy = gy + dt * fy;
    float wx = gx + dt * fx;
    bool inside = (wy >= 0.0f) && (wy <= (float)(HH - 1)) &&
                  (wx >= 0.0f) && (wx <= (float)(WW - 1));
    if (!inside) return;
    float ty = floorf(wy);
    float lx = floorf(wx);
    int base = b * NN;
#pragma unroll
    for (int k = 0; k < 4; ++k) {
        float ny = ty + (float)(k >> 1);
        float nx = lx + (float)(k & 1);
        int iy = (int)ny;
        int ix = (int)nx;
        if (iy < 0 || iy >= HH || ix < 0 || ix >= WW) continue;
        float wgt_y = fminf(fmaxf(1.0f - fabsf(wy - ny), 0.0f), 1.0f);
        float wgt_x = fminf(fmaxf(1.0f - fabsf(wx - nx), 0.0f), 1.0f);
        float w = wgt_y * wgt_x;
        int fi = base + iy * WW + ix;
        atomic_add_f32(&sum_w[fi],  w);
        atomic_add_f32(&sum_wy[fi], w * fy);
        atomic_add_f32(&sum_wx[fi], w * fx);
    }
}

__global__ void finalize_kernel(const float* __restrict__ sum_w,
                                const float* __restrict__ sum_wy,
                                const float* __restrict__ sum_wx,
                                float* __restrict__ out) {
    int t = blockIdx.x * blockDim.x + threadIdx.x;
    if (t >= BB * NN) return;
    float denom = sum_w[t] + EPS;
    out[t]                   = sum_wx[t] / denom;
    out[(size_t)BB * NN + t] = sum_wy[t] / denom;
}

// ---------------- launch ----------------

extern "C" void kernel_launch(void* const* d_in, const int* in_sizes, int n_in,
                              void* d_out, int out_size, void* d_ws, size_t ws_size,
                              hipStream_t stream) {
    const float* fx_all = (const float*)d_in[0];
    const float* fy_all = (const float*)d_in[1];
    const int* i_ptr    = (const int*)d_in[2];
    const int* tref_ptr = (const int*)d_in[3];
    float* out = (float*)d_out;

    const size_t S_bytes = (size_t)BB * NTILES * SFLOATS * sizeof(float); // ~69.7 MB
    const size_t F_elems = (size_t)BB * NN;
    const size_t F_bytes = F_elems * 3 * sizeof(float);                   // ~29.5 MB

    if (ws_size >= S_bytes + F_bytes) {
        float* S   = (float*)d_ws;
        float* Fw  = (float*)((char*)d_ws + S_bytes);
        float* Fwy = Fw + F_elems;
        float* Fwx = Fwy + F_elems;
        // Zero only the fallback accumulator; S is fully overwritten by flush.
        hipMemsetAsync(Fw, 0, F_bytes, stream);
        splat_stage<<<dim3(NTX, NTY, BB), 256, 0, stream>>>(
            fx_all, fy_all, i_ptr, tref_ptr, S, Fw, Fwy, Fwx);
        int total = BB * NN;
        gather_finalize<<<(total + 255) / 256, 256, 0, stream>>>(S, Fw, Fwy, Fwx, out);
    } else {
        // R1 fallback: plain global-atomic splat
        float* sum_w  = (float*)d_ws;
        float* sum_wy = sum_w + (size_t)BB * NN;
        float* sum_wx = sum_wy + (size_t)BB * NN;
        hipMemsetAsync(d_ws, 0, (size_t)3 * BB * NN * sizeof(float), stream);
        int total = BB * NN;
        int block = 256;
        int grid = (total + block - 1) / block;
        splat_kernel<<<grid, block, 0, stream>>>(fx_all, fy_all, i_ptr, tref_ptr,
                                                 sum_w, sum_wy, sum_wx);
        finalize_kernel<<<grid, block, 0, stream>>>(sum_w, sum_wy, sum_wx, out);
    }
}